// Round 6
// baseline (254.313 us; speedup 1.0000x reference)
//
#include <hip/hip_runtime.h>

// Problem constants
#define HDIM 256
#define WDIM 1216
#define HWC  (HDIM*WDIM)     // 311296
#define NPTS 40000
#define KNN  9
#define CCH  64
#define PIXR 256             // index range of pixel coords (0..255)
#define EPSF 1e-5f

// ---------------------------------------------------------------------------
// Kernel 1: prep — feature transpose (all 1024 blocks) + winner atomicMax
// side-job (first 157 blocks). Both write disjoint memory; winner buffer is
// memset to -1 on-stream before this kernel.
// transpose: CHW -> (iy,ix,c) for ix<256; LDS-tiled, +1 pad, coalesced both sides.
// ---------------------------------------------------------------------------
__global__ __launch_bounds__(256) void prep_k(const float* __restrict__ feat,
                                              float* __restrict__ feat_t,
                                              const int* __restrict__ pix,
                                              int* __restrict__ winner) {
    __shared__ float tile[64][65];
    const int iy   = blockIdx.x >> 2;
    const int ixb  = (blockIdx.x & 3) * 64;
    const int lane = threadIdx.x & 63;
    const int w    = threadIdx.x >> 6;

    // winner side-job: last-wins per output pixel (numpy assignment semantics)
    const int n = blockIdx.x * 256 + threadIdx.x;
    if (n < NPTS) {
        int px = pix[2 * n];
        int py = pix[2 * n + 1];
        atomicMax(&winner[py * PIXR + px], n);
    }

#pragma unroll
    for (int r = 0; r < 16; ++r) {
        int cc = w * 16 + r;
        tile[cc][lane] = feat[cc * HWC + iy * WDIM + ixb + lane];   // 256B coalesced
    }
    __syncthreads();
#pragma unroll
    for (int r = 0; r < 16; ++r) {
        int ix = w * 16 + r;
        feat_t[(iy * PIXR + ixb + ix) * 64 + lane] = tile[lane][ix]; // 256B coalesced
    }
}

// ---------------------------------------------------------------------------
// Kernel 2: fused point kernel. Wave per point, 4 points/wave, 16/block.
// Phase A: hmid (288 vals) once per wave into wave-private LDS.
// Phase B: lane=c; wts[k,c] via ds_read_b128 broadcast vs w2col regs; msg.
// Phase C: 1x1 conv — msg to wave-private LDS, broadcast vs cw regs
//          (4 accumulators to break the 64-FMA dependent chain).
// BN partial sums -> block reduce -> 1 atomicAdd pair per channel.
// Wave-private LDS + in-order DS pipe -> no intra-loop barriers (proven R5).
// ---------------------------------------------------------------------------
__global__ __launch_bounds__(256, 3) void point_k(
    const float* __restrict__ feat_t,   // [256*256, 64]
    const float* __restrict__ diff,     // [N, 9, 3]
    const int*   __restrict__ nnpix,    // [N, 9, 2]
    const float* __restrict__ W1,       // [3, 32]
    const float* __restrict__ b1,       // [32]
    const float* __restrict__ W2,       // [32, 64]
    const float* __restrict__ b2,       // [64]
    const float* __restrict__ conv_w,   // [64, 64] (out, in)
    const float* __restrict__ conv_b,   // [64]
    float* __restrict__ y_buf,          // [N, 64]
    float* __restrict__ sums)           // [128]: sum(y), sum(y^2) per channel
{
    __shared__ float dstage[4][32];     // diff staging (27 used), wave-private
    __shared__ float hl[4][288];        // hmid, wave-private
    __shared__ float msg_lds[4][64];    // msg broadcast, wave-private
    __shared__ float r1[4][64];
    __shared__ float r2[4][64];

    const int l = threadIdx.x & 63;
    const int w = __builtin_amdgcn_readfirstlane(threadIdx.x >> 6);  // scalar
    const int c = l;

    // phase-A per-lane W1 column (j = l&31, loop-invariant)
    const int j = l & 31;
    const float w10 = W1[j], w11 = W1[32 + j], w12 = W1[64 + j], bj = b1[j];

    // phase-B per-lane W2 column
    float w2col[32];                       // W2[:, c]
#pragma unroll
    for (int jj = 0; jj < 32; ++jj) w2col[jj] = W2[jj * 64 + c];
    const float b2c = b2[c];

    // phase-C per-lane conv row
    float4 cw[16];                         // conv_w[c, :]
    const float4* cwrow = (const float4*)(conv_w + c * 64);
#pragma unroll
    for (int q = 0; q < 16; ++q) cw[q] = cwrow[q];
    const float cbc = conv_b[c];

    float s1 = 0.f, s2 = 0.f;

    for (int g = 0; g < 4; ++g) {
        const int n = blockIdx.x * 16 + g * 4 + w;   // scalar point index

        // --- gather neighbor features early (latency hidden under A/B) ---
        const int* qi = nnpix + n * 18;              // wave-uniform -> s_load
        float fval[KNN];
#pragma unroll
        for (int k = 0; k < KNN; ++k) {
            int ix = qi[2 * k];
            int iy = qi[2 * k + 1];
            fval[k] = feat_t[(iy * PIXR + ix) * 64 + c];   // 256B coalesced
        }

        // --- phase A: hmid[idx = k*32+j] = relu(diff[n][k].W1[:,j] + b1[j]) ---
        if (l < 27) dstage[w][l] = diff[n * 27 + l]; // wave-private stage
#pragma unroll
        for (int i = 0; i < 5; ++i) {
            int idx = l + 64 * i;
            if (idx < 288) {
                int k = idx >> 5;
                float d0 = dstage[w][k * 3 + 0];
                float d1 = dstage[w][k * 3 + 1];
                float d2 = dstage[w][k * 3 + 2];
                float h = fmaf(d0, w10, fmaf(d1, w11, fmaf(d2, w12, bj)));
                hl[w][idx] = fmaxf(h, 0.f);
            }
        }

        // --- phase B: wts + weighted neighbor sum (hmid via b128 broadcast) ---
        const float4* hp = (const float4*)hl[w];
        float msg = 0.f;
#pragma unroll
        for (int k = 0; k < KNN; ++k) {
            float a0 = b2c, a1 = 0.f, a2 = 0.f, a3 = 0.f;  // 4 chains
#pragma unroll
            for (int q = 0; q < 8; ++q) {
                float4 h = hp[k * 8 + q];                  // ds_read_b128 broadcast
                a0 = fmaf(h.x, w2col[4 * q + 0], a0);
                a1 = fmaf(h.y, w2col[4 * q + 1], a1);
                a2 = fmaf(h.z, w2col[4 * q + 2], a2);
                a3 = fmaf(h.w, w2col[4 * q + 3], a3);
            }
            float wt = fmaxf((a0 + a1) + (a2 + a3), 0.f);
            msg = fmaf(wt, fval[k], msg);
        }

        // --- phase C: 1x1 conv via wave-private LDS broadcast, 4 acc chains ---
        msg_lds[w][c] = msg;
        const float4* ml = (const float4*)msg_lds[w];
        float y0 = cbc, y1 = 0.f, y2 = 0.f, y3 = 0.f;
#pragma unroll
        for (int q = 0; q < 16; ++q) {
            float4 m4 = ml[q];                       // ds_read_b128 broadcast
            float4 c4 = cw[q];
            y0 = fmaf(m4.x, c4.x, y0);
            y1 = fmaf(m4.y, c4.y, y1);
            y2 = fmaf(m4.z, c4.z, y2);
            y3 = fmaf(m4.w, c4.w, y3);
        }
        float y = (y0 + y1) + (y2 + y3);

        s1 += y;
        s2 = fmaf(y, y, s2);
        y_buf[n * 64 + c] = y;                       // 256B coalesced
    }

    // --- block reduction of BN partials, one atomicAdd pair per lane of wave 0 ---
    r1[w][c] = s1;
    r2[w][c] = s2;
    __syncthreads();
    if (w == 0) {
        float a  = r1[0][c] + r1[1][c] + r1[2][c] + r1[3][c];
        float bb = r2[0][c] + r2[1][c] + r2[2][c] + r2[3][c];
        atomicAdd(&sums[c], a);
        atomicAdd(&sums[64 + c], bb);
    }
}

// ---------------------------------------------------------------------------
// Kernel 3: full-image writer with inline BN-stat folding (stats_k fused in:
// every block recomputes the per-channel affine from sums — 8 uniform loads
// + ~15 VALU, cheaper than a separate dispatch). Block = (c,y) output row;
// lanes along x -> every store coalesced.
// ---------------------------------------------------------------------------
__global__ __launch_bounds__(256) void write_k(
    const float* __restrict__ y_buf,   // [N, 64] pre-BN
    const float* __restrict__ sums,    // [128]
    const float* __restrict__ gamma,   // [64]
    const float* __restrict__ beta,    // [64]
    const int*   __restrict__ winner,  // [256*256]
    float* __restrict__ out)           // [64, 256, 1216]
{
    const int c = blockIdx.x & 63;
    const int y = blockIdx.x >> 6;
    const int t = threadIdx.x;

    // inline stats fold (wave-uniform)
    const float inv_n = 1.f / (float)NPTS;
    float mean = sums[c] * inv_n;
    float var  = sums[64 + c] * inv_n - mean * mean;
    float rstd = rsqrtf(var + EPSF);
    float A = gamma[c] * rstd;
    float B = beta[c] - mean * A;

    float* row = out + c * HWC + y * WDIM;
    int wn = winner[y * PIXR + t];             // coalesced 1KB
    float v = 0.f;
    if (wn >= 0) {
        float yv = y_buf[wn * 64 + c];         // scattered 4B (L2/L3 resident)
        v = fmaxf(fmaf(A, yv, B), 0.f);
    }
    row[t] = v;                                // coalesced 1KB
    if (t < 240) {                             // zero x = 256..1215
        float4 z = {0.f, 0.f, 0.f, 0.f};
        ((float4*)(row + 256))[t] = z;         // coalesced 3840B
    }
}

// ---------------------------------------------------------------------------
extern "C" void kernel_launch(void* const* d_in, const int* in_sizes, int n_in,
                              void* d_out, int out_size, void* d_ws, size_t ws_size,
                              hipStream_t stream) {
    const float* feat   = (const float*)d_in[0];   // [1,64,256,1216]
    const float* diff   = (const float*)d_in[1];   // [1,40000,9,3]
    const int*   pix    = (const int*)  d_in[2];   // [1,40000,2]
    const int*   nnpix  = (const int*)  d_in[3];   // [1,40000,9,2]
    const float* W1     = (const float*)d_in[4];   // [3,32]
    const float* b1v    = (const float*)d_in[5];   // [32]
    const float* W2     = (const float*)d_in[6];   // [32,64]
    const float* b2v    = (const float*)d_in[7];   // [64]
    const float* conv_w = (const float*)d_in[8];   // [64,64]
    const float* conv_b = (const float*)d_in[9];   // [64]
    const float* gamma  = (const float*)d_in[10];  // [64]
    const float* beta   = (const float*)d_in[11];  // [64]
    float* out = (float*)d_out;

    // workspace layout (bytes) — within proven 37,520,384 B footprint:
    //   feat_t : 0        .. 16777216    (256*256*64 f32)
    //   y_buf  : 16777216 .. 27017216    (40000*64 f32)
    //   sums   : 27017216 .. 27017728    (128 f32)
    //   winner : 27017728 .. 27279872    (256*256 i32)
    char* ws = (char*)d_ws;
    float* feat_t  = (float*)(ws);
    float* y_buf   = (float*)(ws + 16777216);
    float* sums    = (float*)(ws + 27017216);
    int*   winner  = (int*)  (ws + 27017728);

    hipMemsetAsync(sums, 0, 128 * sizeof(float), stream);
    hipMemsetAsync(winner, 0xFF, PIXR * PIXR * sizeof(int), stream);  // -1

    prep_k<<<1024, 256, 0, stream>>>(feat, feat_t, pix, winner);
    point_k<<<2500, 256, 0, stream>>>(feat_t, diff, nnpix, W1, b1v, W2, b2v,
                                      conv_w, conv_b, y_buf, sums);
    write_k<<<16384, 256, 0, stream>>>(y_buf, sums, gamma, beta, winner, out);
}

// Round 7
// 246.792 us; speedup vs baseline: 1.0305x; 1.0305x over previous
//
#include <hip/hip_runtime.h>

// Problem constants
#define HDIM 256
#define WDIM 1216
#define HWC  (HDIM*WDIM)     // 311296
#define NPTS 40000
#define KNN  9
#define PIXR 256             // index range of pixel coords (0..255)
#define EPSF 1e-5f

typedef __attribute__((ext_vector_type(8))) short bf16x8;
typedef __attribute__((ext_vector_type(4))) float f32x4;

static __device__ __forceinline__ unsigned short f2bf(float f) {
    unsigned int u = __float_as_uint(f);
    u += 0x7FFFu + ((u >> 16) & 1u);     // round-nearest-even
    return (unsigned short)(u >> 16);
}

// ---------------------------------------------------------------------------
// Kernel 1: prep — feature transpose (1024 blocks) + winner atomicMax side-job
// (first 157 blocks). Unchanged from R6 (proven).
// ---------------------------------------------------------------------------
__global__ __launch_bounds__(256) void prep_k(const float* __restrict__ feat,
                                              float* __restrict__ feat_t,
                                              const int* __restrict__ pix,
                                              int* __restrict__ winner) {
    __shared__ float tile[64][65];
    const int iy   = blockIdx.x >> 2;
    const int ixb  = (blockIdx.x & 3) * 64;
    const int lane = threadIdx.x & 63;
    const int w    = threadIdx.x >> 6;

    const int n = blockIdx.x * 256 + threadIdx.x;
    if (n < NPTS) {
        int px = pix[2 * n];
        int py = pix[2 * n + 1];
        atomicMax(&winner[py * PIXR + px], n);
    }

#pragma unroll
    for (int r = 0; r < 16; ++r) {
        int cc = w * 16 + r;
        tile[cc][lane] = feat[cc * HWC + iy * WDIM + ixb + lane];
    }
    __syncthreads();
#pragma unroll
    for (int r = 0; r < 16; ++r) {
        int ix = w * 16 + r;
        feat_t[(iy * PIXR + ixb + ix) * 64 + lane] = tile[lane][ix];
    }
}

// ---------------------------------------------------------------------------
// Kernel 2: MFMA point kernel. ONE WAVE per block (no barriers at all),
// 16 points per wave, grid 2500.
//  Phase A: hmid[k,j] (bf16 pairs) into LDS, rows padded to 16 (rows 9-15 = 0).
//  Phase B: wts tile = mfma(A=hmid[16,32], B=W2[32,16m]) + b2 (C-init);
//           partial[c'] = sum_i relu(D[i]) * f[n, k=4q+i, c'] (f gathered in
//           D-layout; padded rows have f=0). Quad-reduce via LDS part buffer.
//  Phase C: batched conv: y[16n,64c] = mfma(A=msg[16,64], B=conv_w^T) + conv_b
//           — 2 A-frag reads + 8 MFMAs per 16 points.
//  BN partials in registers; shfl cross-quad reduce; atomicAdd per block.
// ---------------------------------------------------------------------------
__global__ __launch_bounds__(64) void point_k(
    const float* __restrict__ feat_t,   // [256*256, 64]
    const float* __restrict__ diff,     // [N, 9, 3]
    const int*   __restrict__ nnpix,    // [N, 9, 2]
    const float* __restrict__ W1,       // [3, 32]
    const float* __restrict__ b1,       // [32]
    const float* __restrict__ W2,       // [32, 64]
    const float* __restrict__ b2,       // [64]
    const float* __restrict__ conv_w,   // [64, 64] (out, in)
    const float* __restrict__ conv_b,   // [64]
    float* __restrict__ y_buf,          // [N, 64]
    float* __restrict__ sums)           // [128]
{
    __shared__ float dstage[448];            // diff for 16 points (432 used)
    __shared__ int   npx[288];               // nnpix for 16 points
    __shared__ unsigned int hl[320];         // hmid [16 rows][20 u32], 80B row stride
    __shared__ float part[256];              // [64 c'][4 quads]
    __shared__ unsigned short msgst[1152];   // msg [16 n][72 u16], 144B row stride

    const int l   = threadIdx.x;
    const int q   = l >> 4;
    const int col = l & 15;
    const int nbase = blockIdx.x * 16;

    // ---- persistent fragments (loaded once) ----
    // W2 B-frag: B[j = 8q+t][c' = col+16m]
    bf16x8 bw2[4];
#pragma unroll
    for (int m = 0; m < 4; ++m)
#pragma unroll
        for (int t = 0; t < 8; ++t)
            bw2[m][t] = (short)f2bf(W2[(q * 8 + t) * 64 + col + 16 * m]);
    // conv B-frag: B[c' = 32h+8q+t][c = col+16m] = conv_w[c][c']
    bf16x8 bcv[4][2];
#pragma unroll
    for (int m = 0; m < 4; ++m)
#pragma unroll
        for (int h = 0; h < 2; ++h)
#pragma unroll
            for (int t = 0; t < 8; ++t)
                bcv[m][h][t] = (short)f2bf(conv_w[(col + 16 * m) * 64 + h * 32 + q * 8 + t]);

    float b2m[4], cbm[4];
#pragma unroll
    for (int m = 0; m < 4; ++m) { b2m[m] = b2[col + 16 * m]; cbm[m] = conv_b[col + 16 * m]; }

    // W1 columns for phase A (jp = col fixed per lane -> j0 = 2*col, j0+1)
    const int j0 = 2 * col;
    const float wa0 = W1[j0],     wa1 = W1[32 + j0],     wa2 = W1[64 + j0],     ba = b1[j0];
    const float wb0 = W1[j0 + 1], wb1 = W1[32 + j0 + 1], wb2 = W1[64 + j0 + 1], bb = b1[j0 + 1];

    // preload diff + nnpix for the wave's 16 points (coalesced)
#pragma unroll
    for (int t = 0; t < 7; ++t) { int idx = l + 64 * t; if (idx < 432) dstage[idx] = diff[nbase * 27 + idx]; }
#pragma unroll
    for (int t = 0; t < 5; ++t) { int idx = l + 64 * t; if (idx < 288) npx[idx] = nnpix[nbase * 18 + idx]; }

    // zero hmid pad rows 9..15 once (phase A never writes them)
    for (int z = 180 + l; z < 320; z += 64) hl[z] = 0;

    float s1[4] = {0.f, 0.f, 0.f, 0.f}, s2[4] = {0.f, 0.f, 0.f, 0.f};

    for (int g = 0; g < 16; ++g) {
        // --- gather f in D-layout: fval[m][i] = f[n, k=4q+i, c'=col+16m] ---
        float fval[4][4];
#pragma unroll
        for (int i = 0; i < 4; ++i) {
            int k = q * 4 + i;
#pragma unroll
            for (int m = 0; m < 4; ++m) fval[m][i] = 0.f;
            if (k < 9) {
                int px = npx[(g * 9 + k) * 2];
                int py = npx[(g * 9 + k) * 2 + 1];
                const float* fb = feat_t + (py * PIXR + px) * 64 + col;
#pragma unroll
                for (int m = 0; m < 4; ++m) fval[m][i] = fb[16 * m];
            }
        }

        // --- phase A: hmid[k2][2*col, 2*col+1] once per point ---
#pragma unroll
        for (int i2 = 0; i2 < 3; ++i2) {
            int k2 = q + 4 * i2;          // covers k 0..8 exactly
            if (k2 < 9) {
                float d0 = dstage[g * 27 + k2 * 3];
                float d1 = dstage[g * 27 + k2 * 3 + 1];
                float d2 = dstage[g * 27 + k2 * 3 + 2];
                float h0 = fmaxf(fmaf(d0, wa0, fmaf(d1, wa1, fmaf(d2, wa2, ba))), 0.f);
                float h1 = fmaxf(fmaf(d0, wb0, fmaf(d1, wb1, fmaf(d2, wb2, bb))), 0.f);
                hl[k2 * 20 + col] = (unsigned int)f2bf(h0) | ((unsigned int)f2bf(h1) << 16);
            }
        }

        // --- phase B: wts via MFMA, then weighted neighbor sum ---
        bf16x8 a;
        {
            uint4 av = *(const uint4*)((const char*)hl + col * 80 + q * 16);
            a = __builtin_bit_cast(bf16x8, av);
        }
#pragma unroll
        for (int m = 0; m < 4; ++m) {
            f32x4 acc = {b2m[m], b2m[m], b2m[m], b2m[m]};
            acc = __builtin_amdgcn_mfma_f32_16x16x32_bf16(a, bw2[m], acc, 0, 0, 0);
            float p = 0.f;
#pragma unroll
            for (int i = 0; i < 4; ++i)
                p = fmaf(fmaxf(acc[i], 0.f), fval[m][i], p);
            part[(col + 16 * m) * 4 + q] = p;     // quad partials
        }
        float4 pr = *(const float4*)&part[l * 4]; // lane l = channel c'
        float msg = (pr.x + pr.y) + (pr.z + pr.w);
        msgst[g * 72 + l] = f2bf(msg);
    }

    // --- phase C: batched 1x1 conv over the 16 points ---
    bf16x8 am[2];
#pragma unroll
    for (int h = 0; h < 2; ++h) {
        uint4 av = *(const uint4*)((const char*)msgst + col * 144 + h * 64 + q * 16);
        am[h] = __builtin_bit_cast(bf16x8, av);
    }
#pragma unroll
    for (int m = 0; m < 4; ++m) {
        f32x4 acc = {cbm[m], cbm[m], cbm[m], cbm[m]};
        acc = __builtin_amdgcn_mfma_f32_16x16x32_bf16(am[0], bcv[m][0], acc, 0, 0, 0);
        acc = __builtin_amdgcn_mfma_f32_16x16x32_bf16(am[1], bcv[m][1], acc, 0, 0, 0);
#pragma unroll
        for (int i = 0; i < 4; ++i) {
            float y = acc[i];                        // row n_local = 4q+i, col c
            y_buf[(nbase + q * 4 + i) * 64 + col + 16 * m] = y;
            s1[m] += y;
            s2[m] = fmaf(y, y, s2[m]);
        }
    }

    // --- BN partials: cross-quad shfl reduce, atomics from quad 0 ---
#pragma unroll
    for (int m = 0; m < 4; ++m) {
        float a1 = s1[m], a2 = s2[m];
        a1 += __shfl_xor(a1, 16); a1 += __shfl_xor(a1, 32);
        a2 += __shfl_xor(a2, 16); a2 += __shfl_xor(a2, 32);
        if (q == 0) {
            atomicAdd(&sums[col + 16 * m], a1);
            atomicAdd(&sums[64 + col + 16 * m], a2);
        }
    }
}

// ---------------------------------------------------------------------------
// Kernel 3: full-image writer, c-chunked. Block = (y row, chunk of 16 c):
// the 16 c values of a chunk span exactly one 64B y_buf line per point, so
// gather lines are L1-resident across the cc-loop (L2 traffic 160MB -> 16MB).
// Inline BN-stat fold per c. All stores coalesced.
// ---------------------------------------------------------------------------
__global__ __launch_bounds__(256) void write_k(
    const float* __restrict__ y_buf,   // [N, 64] pre-BN
    const float* __restrict__ sums,    // [128]
    const float* __restrict__ gamma,   // [64]
    const float* __restrict__ beta,    // [64]
    const int*   __restrict__ winner,  // [256*256]
    float* __restrict__ out)           // [64, 256, 1216]
{
    const int y  = blockIdx.x >> 2;
    const int ch = (blockIdx.x & 3) * 16;
    const int t  = threadIdx.x;
    const float inv_n = 1.f / (float)NPTS;

    const int wn = winner[y * PIXR + t];       // coalesced 1KB, kept in VGPR
#pragma unroll
    for (int cc = 0; cc < 16; ++cc) {
        int c = ch + cc;
        float mean = sums[c] * inv_n;
        float var  = sums[64 + c] * inv_n - mean * mean;
        float rstd = rsqrtf(var + EPSF);
        float A = gamma[c] * rstd;
        float B = beta[c] - mean * A;

        float v = 0.f;
        if (wn >= 0) v = fmaxf(fmaf(A, y_buf[wn * 64 + c], B), 0.f);
        float* row = out + c * HWC + y * WDIM;
        row[t] = v;                            // coalesced 1KB
        if (t < 240) {
            float4 z = {0.f, 0.f, 0.f, 0.f};
            ((float4*)(row + 256))[t] = z;     // zero x = 256..1215
        }
    }
}

// ---------------------------------------------------------------------------
extern "C" void kernel_launch(void* const* d_in, const int* in_sizes, int n_in,
                              void* d_out, int out_size, void* d_ws, size_t ws_size,
                              hipStream_t stream) {
    const float* feat   = (const float*)d_in[0];   // [1,64,256,1216]
    const float* diff   = (const float*)d_in[1];   // [1,40000,9,3]
    const int*   pix    = (const int*)  d_in[2];   // [1,40000,2]
    const int*   nnpix  = (const int*)  d_in[3];   // [1,40000,9,2]
    const float* W1     = (const float*)d_in[4];   // [3,32]
    const float* b1v    = (const float*)d_in[5];   // [32]
    const float* W2     = (const float*)d_in[6];   // [32,64]
    const float* b2v    = (const float*)d_in[7];   // [64]
    const float* conv_w = (const float*)d_in[8];   // [64,64]
    const float* conv_b = (const float*)d_in[9];   // [64]
    const float* gamma  = (const float*)d_in[10];  // [64]
    const float* beta   = (const float*)d_in[11];  // [64]
    float* out = (float*)d_out;

    // workspace layout (bytes) — within proven 37.5 MB footprint:
    //   feat_t : 0        .. 16777216    (256*256*64 f32)
    //   y_buf  : 16777216 .. 27017216    (40000*64 f32)
    //   sums   : 27017216 .. 27017728    (128 f32)
    //   winner : 27017728 .. 27279872    (256*256 i32)
    char* ws = (char*)d_ws;
    float* feat_t  = (float*)(ws);
    float* y_buf   = (float*)(ws + 16777216);
    float* sums    = (float*)(ws + 27017216);
    int*   winner  = (int*)  (ws + 27017728);

    hipMemsetAsync(sums, 0, 128 * sizeof(float), stream);
    hipMemsetAsync(winner, 0xFF, PIXR * PIXR * sizeof(int), stream);  // -1

    prep_k<<<1024, 256, 0, stream>>>(feat, feat_t, pix, winner);
    point_k<<<2500, 64, 0, stream>>>(feat_t, diff, nnpix, W1, b1v, W2, b2v,
                                     conv_w, conv_b, y_buf, sums);
    write_k<<<1024, 256, 0, stream>>>(y_buf, sums, gamma, beta, winner, out);
}